// Round 7
// baseline (515.104 us; speedup 1.0000x reference)
//
#include <hip/hip_runtime.h>
#include <hip/hip_bf16.h>
#include <cstdint>

// ---------------------------------------------------------------------------
// LocalWindowTransformer: windowed MHA, B=4 L=4096 H=1024 NH=16 hd=64 P=128
// R12: delete cvt_x (~43us of residual, proven by R9's subtraction) WITHOUT
//     touching the verified drain-0 loop or occupancy: A-fragments are read
//     DIRECTLY from global f32 (wave reads 16 rows x 256B contiguous -> full
//     coalescing), converted in-register (bit-identical RNE), fed to MFMA.
//     No X LDS staging => no f32 swizzle (R11's 83M bank conflicts), LDS
//     stays 53248B => 3 blocks/CU. X L2 reuse across 16 heads protected by
//     dispatch-order remap: 1D grid, xcd=id%8, heads innermost per window
//     group => per-XCD co-resident X working set ~3MB < 4MB L2.
// MFMA 16x16x32 bf16 layouts (HW-verified per guide):
//   A-frag: lane holds A[m=lane&15][k=(lane>>4)*8+j], j=0..7
//   B-frag: lane holds B_hw[k=(lane>>4)*8+j][n=lane&15]
//   C/D   : reg r holds C[row=(lane>>4)*4+r][col=lane&15]
// W staging swizzle (bf16, BK=64): row r, 16B-position p holds chunk p^(r&7);
//   fragment read at ((half*4+q4)^(r&7))*8 elems.
// ---------------------------------------------------------------------------

typedef __bf16 bf16_t;
typedef __bf16 bf16x8 __attribute__((ext_vector_type(8)));
typedef __bf16 bf16x4 __attribute__((ext_vector_type(4)));
typedef float  floatx4 __attribute__((ext_vector_type(4)));

#define MFMA_16x16x32(A, B, C) __builtin_amdgcn_mfma_f32_16x16x32_bf16(A, B, C, 0, 0, 0)

// async global->LDS, 16B per lane; LDS dest = wave-uniform base + lane*16
__device__ __forceinline__ void gld_lds16(const bf16_t* g, bf16_t* l) {
  __builtin_amdgcn_global_load_lds(
      (__attribute__((address_space(1))) void*)(void*)(g),
      (__attribute__((address_space(3))) void*)(l), 16, 0, 0);
}

__device__ __forceinline__ void cvt8(const float* __restrict__ s,
                                     bf16_t* __restrict__ d) {
  float4 a = ((const float4*)s)[0];
  float4 b = ((const float4*)s)[1];
  bf16x8 o;
  o[0] = (bf16_t)a.x; o[1] = (bf16_t)a.y; o[2] = (bf16_t)a.z; o[3] = (bf16_t)a.w;
  o[4] = (bf16_t)b.x; o[5] = (bf16_t)b.y; o[6] = (bf16_t)b.z; o[7] = (bf16_t)b.w;
  *(bf16x8*)d = o;
}

// ---------------------------------------------------------------------------
// Weights-only conversion, 8-elem chunks (x never converted at all now):
//   [0, 131072)      Wout [1024,1024]  -> Woutb
//   [131072, 524288) Win  [3072,1024]  -> Wpk (head-packed repack)
__global__ void cvt_w(const float* __restrict__ Win,
                      const float* __restrict__ Wout,
                      bf16_t* __restrict__ Wpk,
                      bf16_t* __restrict__ Woutb) {
  const int idx = blockIdx.x * 256 + threadIdx.x;
  if (idx < 131072) {
    cvt8(Wout + (size_t)idx * 8, Woutb + (size_t)idx * 8);
  } else {
    const int c = idx - 131072;           // 0..393215
    const int dr = c >> 7, i = c & 127;   // packed row, chunk-in-row
    const int head = dr / 192, s = dr - head * 192;
    const int src = (s < 64) ? head * 64 + s
                  : (s < 128) ? 1024 + head * 64 + (s - 64)
                              : 2048 + head * 64 + (s - 128);
    cvt8(Win + (size_t)src * 1024 + i * 8, Wpk + (size_t)dr * 1024 + i * 8);
  }
}

// ---------------------------------------------------------------------------
// Out-projection GEMM (R5 config, session-best): BM=128, BN=256, BK=64,
// swizzled staging. grid(4,128)=512 blocks = 2/CU. Wave tile 64x128.
__global__ __launch_bounds__(256, 2) void gemm_out(
    const bf16_t* __restrict__ A, const bf16_t* __restrict__ Bm,
    const float* __restrict__ bias, float* __restrict__ C,
    int M, int N, int K) {
  __shared__ bf16_t As[128 * 64];   // 16 KB
  __shared__ bf16_t Bs[256 * 64];   // 32 KB
  const int tid  = threadIdx.x;
  const int lane = tid & 63;
  const int wave = tid >> 6;
  const int n16  = lane & 15;
  const int q4   = lane >> 4;
  const int wm   = (wave >> 1) * 64;
  const int wn   = (wave & 1) * 128;
  const int m0   = blockIdx.y * 128;
  const int n0   = blockIdx.x * 256;

  floatx4 acc[4][8] = {};

  for (int k0 = 0; k0 < K; k0 += 64) {
    __syncthreads();
#pragma unroll
    for (int it = 0; it < 4; ++it) {       // As: 1024 chunks of 8
      const int ch = it * 256 + tid;
      const int r  = ch >> 3;
      const int c8 = (ch & 7) ^ (r & 7);
      gld_lds16(A + (size_t)(m0 + r) * K + k0 + c8 * 8,
                As + (it * 256 + wave * 64) * 8);
    }
#pragma unroll
    for (int it = 0; it < 8; ++it) {       // Bs: 2048 chunks of 8
      const int ch = it * 256 + tid;
      const int r  = ch >> 3;
      const int c8 = (ch & 7) ^ (r & 7);
      gld_lds16(Bm + (size_t)(n0 + r) * K + k0 + c8 * 8,
                Bs + (it * 256 + wave * 64) * 8);
    }
    __syncthreads();

#pragma unroll
    for (int half = 0; half < 2; ++half) {
      bf16x8 af[4], bfr[8];
#pragma unroll
      for (int i = 0; i < 4; ++i) {
        const int row = wm + i * 16 + n16;
        af[i] = *(const bf16x8*)&As[row * 64 + (((half * 4 + q4) ^ (row & 7)) * 8)];
      }
#pragma unroll
      for (int j = 0; j < 8; ++j) {
        const int row = wn + j * 16 + n16;
        bfr[j] = *(const bf16x8*)&Bs[row * 64 + (((half * 4 + q4) ^ (row & 7)) * 8)];
      }
#pragma unroll
      for (int i = 0; i < 4; ++i)
#pragma unroll
        for (int j = 0; j < 8; ++j)
          acc[i][j] = MFMA_16x16x32(af[i], bfr[j], acc[i][j]);
    }
  }

#pragma unroll
  for (int i = 0; i < 4; ++i)
#pragma unroll
    for (int j = 0; j < 8; ++j) {
      const int col = n0 + wn + j * 16 + n16;
      const float b = bias[col];
#pragma unroll
      for (int r = 0; r < 4; ++r) {
        const int row = m0 + wm + i * 16 + q4 * 4 + r;
        C[(size_t)row * N + col] = acc[i][j][r] + b;
      }
    }
}

// ---------------------------------------------------------------------------
// Fused QKV-projection + windowed attention. Phase 1: A-fragments read
// DIRECTLY from global f32 (coalesced 16 rows x 256B per wave-fragment,
// L2-resident via dispatch-order remap), cvt'd in-register; W staged via
// gld_lds as in R0. Drain-0 2-barrier loop (verified structure). Phase 2
// unchanged. LDS: Ws[192][64] (24576B) aliased by attn region -> 53248B,
// 3 blocks/CU.
// Grid: 1D 2048. id%8 = XCD; per XCD, heads innermost within window groups:
//   xcd=id%8, t=id/8, widx=t>>4, h=t&15, wid=xcd+8*widx.
// Co-resident ~96 blocks/XCD span ~6 windows => X working set ~3MB < L2.
__global__ __launch_bounds__(256, 3) void qkv_attn(
    const float* __restrict__ Xf,    // [16384,1024] f32
    const bf16_t* __restrict__ Wpk,  // [16][192][1024]
    const float* __restrict__ bin,   // [3072]
    bf16_t* __restrict__ o)          // [16384,1024] merged heads
{
  __shared__ bf16_t smem[26624];     // 53248 B
  bf16_t* Ws  = smem;                // [192][64] staging (phase 1 only, 12288 el)
  bf16_t* qs  = smem;                // [128][72] (aliases staging, post-barrier)
  bf16_t* ks  = smem + 9216;         // [128][72]
  bf16_t* vsT = smem + 18432;        // [64][128] XOR-swizzled
  bf16_t* Ps  = smem;                // [128][136] = 17408 <= 18432 (qs+ks)

  const int id   = blockIdx.x;
  const int xcd  = id & 7;
  const int t    = id >> 3;
  const int h    = t & 15;           // head 0..15 (innermost per XCD)
  const int wid  = xcd + 8 * (t >> 4);  // window 0..127
  const int tid  = threadIdx.x;
  const int lane = tid & 63;
  const int wave = tid >> 6;
  const int n16  = lane & 15;
  const int q4   = lane >> 4;
  const int wm   = (wave >> 1) * 64;   // wave M-offset (0/64)
  const int wn   = (wave & 1) * 96;    // wave N-offset (0/96)

  const float*  Xg = Xf + (size_t)wid * 128 * 1024;
  const bf16_t* Wg = Wpk + (size_t)h * 192 * 1024;

  // ---- phase 1: qkv = x @ W^T   (M=128, N=192, K=1024, BK=64)
  floatx4 acc[4][6] = {};
  for (int k0 = 0; k0 < 1024; k0 += 64) {
    __syncthreads();
#pragma unroll
    for (int it = 0; it < 6; ++it) {  // W: 1536 chunks of 8 (async -> LDS)
      const int ch = it * 256 + tid;
      const int r  = ch >> 3;
      const int c8 = (ch & 7) ^ (r & 7);
      gld_lds16(Wg + (size_t)r * 1024 + k0 + c8 * 8,
                Ws + (it * 256 + wave * 64) * 8);
    }
    __syncthreads();

#pragma unroll
    for (int half = 0; half < 2; ++half) {
      const int kq = half * 4 + q4;
      bf16x8 af[4], bfr[6];
#pragma unroll
      for (int i = 0; i < 4; ++i) {   // A direct from global f32, cvt in-reg
        const int row = wm + i * 16 + n16;
        const float4* xp = (const float4*)(Xg + (size_t)row * 1024 + k0 + kq * 8);
        float4 lo = xp[0], hi = xp[1];
        bf16x8 v;
        v[0] = (bf16_t)lo.x; v[1] = (bf16_t)lo.y;
        v[2] = (bf16_t)lo.z; v[3] = (bf16_t)lo.w;
        v[4] = (bf16_t)hi.x; v[5] = (bf16_t)hi.y;
        v[6] = (bf16_t)hi.z; v[7] = (bf16_t)hi.w;
        af[i] = v;
      }
#pragma unroll
      for (int j = 0; j < 6; ++j) {
        const int row = wn + j * 16 + n16;
        bfr[j] = *(const bf16x8*)&Ws[row * 64 + ((kq ^ (row & 7)) * 8)];
      }
#pragma unroll
      for (int i = 0; i < 4; ++i)
#pragma unroll
        for (int j = 0; j < 6; ++j)
          acc[i][j] = MFMA_16x16x32(af[i], bfr[j], acc[i][j]);
    }
  }
  __syncthreads();  // staging region dead -> qs/ks/vsT may alias it

  // ---- epilogue: scatter acc -> qs (scaled), ks, vsT (swizzled transpose)
#pragma unroll
  for (int j = 0; j < 6; ++j) {
    const int base = wn + j * 16;   // wave-uniform
    const int col  = base + n16;    // 0..191
    const int gb = (base < 64) ? h * 64 + col
                 : (base < 128) ? 1024 + h * 64 + (col - 64)
                                : 2048 + h * 64 + (col - 128);
    const float bias = bin[gb];
#pragma unroll
    for (int i = 0; i < 4; ++i) {
      const int row0 = wm + i * 16 + q4 * 4;
      if (base < 64) {        // q, fold softmax scale 1/sqrt(64)
#pragma unroll
        for (int r = 0; r < 4; ++r)
          qs[(row0 + r) * 72 + col] = (bf16_t)((acc[i][j][r] + bias) * 0.125f);
      } else if (base < 128) {  // k
#pragma unroll
        for (int r = 0; r < 4; ++r)
          ks[(row0 + r) * 72 + (col - 64)] = (bf16_t)(acc[i][j][r] + bias);
      } else {                  // v -> transposed [dim][token], swizzled
        bf16x4 pv;
#pragma unroll
        for (int r = 0; r < 4; ++r) pv[r] = (bf16_t)(acc[i][j][r] + bias);
        const int d = col - 128;          // dim 0..63; d&15 == n16
        const int c8 = row0 >> 3, pos = row0 & 7;
        *(bf16x4*)&vsT[d * 128 + ((c8 ^ n16) << 3) + pos] = pv;
      }
    }
  }
  __syncthreads();

  // ---- S = q k^T  (wave w owns S rows [32w, 32w+32), K=64)
  floatx4 sacc[2][8] = {};
#pragma unroll
  for (int ks0 = 0; ks0 < 2; ++ks0) {
    bf16x8 aq[2];
#pragma unroll
    for (int i = 0; i < 2; ++i)
      aq[i] = *(const bf16x8*)&qs[(wave * 32 + i * 16 + n16) * 72 + ks0 * 32 + q4 * 8];
#pragma unroll
    for (int j = 0; j < 8; ++j) {
      bf16x8 bk = *(const bf16x8*)&ks[(j * 16 + n16) * 72 + ks0 * 32 + q4 * 8];
      sacc[0][j] = MFMA_16x16x32(aq[0], bk, sacc[0][j]);
      sacc[1][j] = MFMA_16x16x32(aq[1], bk, sacc[1][j]);
    }
  }
  __syncthreads();  // q/k reads done; Ps may overwrite their LDS

  // ---- softmax: no max-sub (logits bounded), P unnormalized, defer 1/sum
  float invs[2][4];
#pragma unroll
  for (int i = 0; i < 2; ++i) {
#pragma unroll
    for (int r = 0; r < 4; ++r) {
      float vals[8];
      float s = 0.f;
#pragma unroll
      for (int j = 0; j < 8; ++j) {
        vals[j] = __expf(sacc[i][j][r]);
        s += vals[j];
      }
      for (int m = 1; m < 16; m <<= 1) s += __shfl_xor(s, m, 64);
      invs[i][r] = 1.0f / s;
      const int prow = wave * 32 + i * 16 + q4 * 4 + r;
#pragma unroll
      for (int j = 0; j < 8; ++j)
        Ps[prow * 136 + j * 16 + n16] = (bf16_t)vals[j];
    }
  }
  __syncthreads();

  // ---- O = P V  (K=128; both operands via ds_read_b128)
  floatx4 oacc[2][4] = {};
#pragma unroll
  for (int kk = 0; kk < 4; ++kk) {
    bf16x8 ap[2];
#pragma unroll
    for (int i = 0; i < 2; ++i)
      ap[i] = *(const bf16x8*)&Ps[(wave * 32 + i * 16 + n16) * 136 + kk * 32 + q4 * 8];
#pragma unroll
    for (int j = 0; j < 4; ++j) {
      const int d = j * 16 + n16;
      bf16x8 bv = *(const bf16x8*)&vsT[d * 128 + (((kk * 4 + q4) ^ n16) << 3)];
      oacc[0][j] = MFMA_16x16x32(ap[0], bv, oacc[0][j]);
      oacc[1][j] = MFMA_16x16x32(ap[1], bv, oacc[1][j]);
    }
  }

  // ---- write o slice (scaled by 1/rowsum), merged-head layout [tok][h*64+d]
  bf16_t* go = o + (size_t)wid * 128 * 1024 + h * 64;
#pragma unroll
  for (int i = 0; i < 2; ++i)
#pragma unroll
    for (int j = 0; j < 4; ++j)
#pragma unroll
      for (int r = 0; r < 4; ++r) {
        const int row = wave * 32 + i * 16 + q4 * 4 + r;
        go[(size_t)row * 1024 + j * 16 + n16] = (bf16_t)(oacc[i][j][r] * invs[i][r]);
      }
}

// ---------------------------------------------------------------------------
extern "C" void kernel_launch(void* const* d_in, const int* in_sizes, int n_in,
                              void* d_out, int out_size, void* d_ws, size_t ws_size,
                              hipStream_t stream) {
  const float* x    = (const float*)d_in[0];
  const float* Win  = (const float*)d_in[1];   // [3072,1024]
  const float* bin  = (const float*)d_in[2];   // [3072]
  const float* Wout = (const float*)d_in[3];   // [1024,1024]
  const float* bout = (const float*)d_in[4];   // [1024]
  float* out = (float*)d_out;

  const size_t M = 16384, H = 1024, H3 = 3072;

  // workspace layout (~40 MB): Wpk | Woutb | ob  (xb eliminated)
  bf16_t* Wpk   = (bf16_t*)d_ws;        // H3*H (head-packed)
  bf16_t* Woutb = Wpk + H3 * H;         // H*H
  bf16_t* ob    = Woutb + H * H;        // M*H

  // weights-only conversion: 524,288 8-elem chunks / 256 = 2048 blocks
  cvt_w<<<dim3(2048), 256, 0, stream>>>(Win, Wout, Wpk, Woutb);

  // 1D grid 2048: xcd=id%8, heads innermost per window group (X L2 reuse).
  qkv_attn<<<dim3(2048), 256, 0, stream>>>(x, Wpk, bin, ob);

  // 512 blocks = one full dispatch round at 2/CU; XCD id%8 pins one B-tile.
  gemm_out<<<dim3((unsigned)(H / 256), (unsigned)(M / 128)), 256, 0, stream>>>(
      ob, Woutb, bout, out, (int)M, (int)H, (int)H);
}

// Round 9
// 278.384 us; speedup vs baseline: 1.8503x; 1.8503x over previous
//
#include <hip/hip_runtime.h>
#include <hip/hip_bf16.h>
#include <cstdint>

// ---------------------------------------------------------------------------
// LocalWindowTransformer: windowed MHA, B=4 L=4096 H=1024 NH=16 hd=64 P=128
// R14 == R13 resubmitted (R8's bench failed on container acquisition, not on
//     the kernel). Full revert to the session-best R0 structure (285.5us):
//     cvt_all + qkv_attn(bf16 X via global_load_lds) + gemm_out(BN=256).
//     Four cvt_x-fusion variants failed for four measured reasons (R9 sync
//     loads +47us; R10 reg-prefetch spill -50%; R11 f32-LDS 83M bank
//     conflicts; R12 in-loop global reads = latency-bound, MfmaUtil 11%).
//     ONE change vs R0: cvt_all is grid-strided at 2048 blocks (was 10240
//     one-chunk-per-thread blocks). Its measured 2.7 TB/s (~43us for 120MB)
//     matches Guideline 11's launch-overhead plateau; capping the grid and
//     looping 5 chunks/thread is the documented fix. Chunk mapping, cvt8
//     numerics, and coalescing are identical -> bit-identical output.
// MFMA 16x16x32 bf16 layouts (HW-verified per guide):
//   A-frag: lane holds A[m=lane&15][k=(lane>>4)*8+j], j=0..7
//   B-frag: lane holds B_hw[k=(lane>>4)*8+j][n=lane&15]
//   C/D   : reg r holds C[row=(lane>>4)*4+r][col=lane&15]
// Swizzled staging layout: LDS row r (64 elems) holds chunk kc at elem
//   offset ((kc ^ (r&7))*8); fragment read addr = r*64 + ((kc^(r&7))*8).
// ---------------------------------------------------------------------------

typedef __bf16 bf16_t;
typedef __bf16 bf16x8 __attribute__((ext_vector_type(8)));
typedef __bf16 bf16x4 __attribute__((ext_vector_type(4)));
typedef float  floatx4 __attribute__((ext_vector_type(4)));

#define MFMA_16x16x32(A, B, C) __builtin_amdgcn_mfma_f32_16x16x32_bf16(A, B, C, 0, 0, 0)

// async global->LDS, 16B per lane; LDS dest = wave-uniform base + lane*16
__device__ __forceinline__ void gld_lds16(const bf16_t* g, bf16_t* l) {
  __builtin_amdgcn_global_load_lds(
      (__attribute__((address_space(1))) void*)(void*)(g),
      (__attribute__((address_space(3))) void*)(l), 16, 0, 0);
}

__device__ __forceinline__ void cvt8(const float* __restrict__ s,
                                     bf16_t* __restrict__ d) {
  float4 a = ((const float4*)s)[0];
  float4 b = ((const float4*)s)[1];
  bf16x8 o;
  o[0] = (bf16_t)a.x; o[1] = (bf16_t)a.y; o[2] = (bf16_t)a.z; o[3] = (bf16_t)a.w;
  o[4] = (bf16_t)b.x; o[5] = (bf16_t)b.y; o[6] = (bf16_t)b.z; o[7] = (bf16_t)b.w;
  *(bf16x8*)d = o;
}

// ---------------------------------------------------------------------------
// One fused conversion pass, grid-strided (G11: cap grid, loop chunks):
//   [0, 2097152)              x    [16384,1024] -> xb
//   [2097152, 2228224)        Wout [1024,1024]  -> Woutb
//   [2228224, 2621440)        Win  [3072,1024]  -> Wpk (head-packed repack)
// 2048 blocks x 256 threads = 524288 threads; 5 chunks/thread.
__global__ void cvt_all(const float* __restrict__ x,
                        const float* __restrict__ Win,
                        const float* __restrict__ Wout,
                        bf16_t* __restrict__ xb,
                        bf16_t* __restrict__ Wpk,
                        bf16_t* __restrict__ Woutb) {
  for (int idx = blockIdx.x * 256 + threadIdx.x; idx < 2621440;
       idx += 2048 * 256) {
    if (idx < 2097152) {
      cvt8(x + (size_t)idx * 8, xb + (size_t)idx * 8);
    } else if (idx < 2228224) {
      const int i = idx - 2097152;
      cvt8(Wout + (size_t)i * 8, Woutb + (size_t)i * 8);
    } else {
      const int c = idx - 2228224;          // 0..393215
      const int dr = c >> 7, i = c & 127;   // packed row, chunk-in-row
      const int head = dr / 192, s = dr - head * 192;
      const int src = (s < 64) ? head * 64 + s
                    : (s < 128) ? 1024 + head * 64 + (s - 64)
                                : 2048 + head * 64 + (s - 128);
      cvt8(Win + (size_t)src * 1024 + i * 8, Wpk + (size_t)dr * 1024 + i * 8);
    }
  }
}

// ---------------------------------------------------------------------------
// Out-projection GEMM: BM=128 x BN=256, BK=64, swizzled staging, 256 threads.
// grid(4,128)=512 blocks = exactly 2/CU (one dispatch round, no tail).
// Wave tile 64x128: acc[4][8] (AGPRs). XCD-affine: id%8 pins one B-tile/XCD.
__global__ __launch_bounds__(256, 2) void gemm_out(
    const bf16_t* __restrict__ A, const bf16_t* __restrict__ Bm,
    const float* __restrict__ bias, float* __restrict__ C,
    int M, int N, int K) {
  __shared__ bf16_t As[128 * 64];   // 16 KB
  __shared__ bf16_t Bs[256 * 64];   // 32 KB
  const int tid  = threadIdx.x;
  const int lane = tid & 63;
  const int wave = tid >> 6;
  const int n16  = lane & 15;
  const int q4   = lane >> 4;
  const int wm   = (wave >> 1) * 64;
  const int wn   = (wave & 1) * 128;
  const int m0   = blockIdx.y * 128;
  const int n0   = blockIdx.x * 256;

  floatx4 acc[4][8] = {};

  for (int k0 = 0; k0 < K; k0 += 64) {
    __syncthreads();
#pragma unroll
    for (int it = 0; it < 4; ++it) {       // As: 1024 chunks of 8
      const int ch = it * 256 + tid;
      const int r  = ch >> 3;
      const int c8 = (ch & 7) ^ (r & 7);
      gld_lds16(A + (size_t)(m0 + r) * K + k0 + c8 * 8,
                As + (it * 256 + wave * 64) * 8);
    }
#pragma unroll
    for (int it = 0; it < 8; ++it) {       // Bs: 2048 chunks of 8
      const int ch = it * 256 + tid;
      const int r  = ch >> 3;
      const int c8 = (ch & 7) ^ (r & 7);
      gld_lds16(Bm + (size_t)(n0 + r) * K + k0 + c8 * 8,
                Bs + (it * 256 + wave * 64) * 8);
    }
    __syncthreads();

#pragma unroll
    for (int half = 0; half < 2; ++half) {
      bf16x8 af[4], bfr[8];
#pragma unroll
      for (int i = 0; i < 4; ++i) {
        const int row = wm + i * 16 + n16;
        af[i] = *(const bf16x8*)&As[row * 64 + (((half * 4 + q4) ^ (row & 7)) * 8)];
      }
#pragma unroll
      for (int j = 0; j < 8; ++j) {
        const int row = wn + j * 16 + n16;
        bfr[j] = *(const bf16x8*)&Bs[row * 64 + (((half * 4 + q4) ^ (row & 7)) * 8)];
      }
#pragma unroll
      for (int i = 0; i < 4; ++i)
#pragma unroll
        for (int j = 0; j < 8; ++j)
          acc[i][j] = MFMA_16x16x32(af[i], bfr[j], acc[i][j]);
    }
  }

#pragma unroll
  for (int i = 0; i < 4; ++i)
#pragma unroll
    for (int j = 0; j < 8; ++j) {
      const int col = n0 + wn + j * 16 + n16;
      const float b = bias[col];
#pragma unroll
      for (int r = 0; r < 4; ++r) {
        const int row = m0 + wm + i * 16 + q4 * 4 + r;
        C[(size_t)row * N + col] = acc[i][j][r] + b;
      }
    }
}

// ---------------------------------------------------------------------------
// Fused QKV-projection + windowed attention (R0 structure, session-best).
// One 256-thread block per (window, head). Phase 1: qkv[128,192] =
// x_win[128,1024] @ Wpk_h^T, BK=64 swizzled staging, drain-0 2-barrier loop.
// Epilogue scatters acc into LDS: q (scaled 1/8, [128][72]), k ([128][72]),
// V transposed into XOR-swizzled [64][128]. Phase 2: S=q k^T; softmax with
// no max-sub (logits bounded), P unnormalized, 1/sum folded into O.
// LDS 53248 B -> 3 blocks/CU.
__global__ __launch_bounds__(256, 3) void qkv_attn(
    const bf16_t* __restrict__ X,    // [16384,1024]
    const bf16_t* __restrict__ Wpk,  // [16][192][1024]
    const float* __restrict__ bin,   // [3072]
    bf16_t* __restrict__ o)          // [16384,1024] merged heads
{
  __shared__ bf16_t smem[26624];     // 53248 B
  bf16_t* Xs  = smem;                // [128][64] staging (phase 1 only)
  bf16_t* Ws  = smem + 8192;         // [192][64] staging (ends 20480)
  bf16_t* qs  = smem;                // [128][72] (aliases staging, post-barrier)
  bf16_t* ks  = smem + 9216;         // [128][72]
  bf16_t* vsT = smem + 18432;        // [64][128] XOR-swizzled
  bf16_t* Ps  = smem;                // [128][136] = 17408 <= 18432 (qs+ks)

  const int wid  = blockIdx.x;       // window 0..127 (XCD-affine: wid%8)
  const int h    = blockIdx.y;       // head 0..15
  const int tid  = threadIdx.x;
  const int lane = tid & 63;
  const int wave = tid >> 6;
  const int n16  = lane & 15;
  const int q4   = lane >> 4;
  const int wm   = (wave >> 1) * 64;   // wave M-offset (0/64)
  const int wn   = (wave & 1) * 96;    // wave N-offset (0/96)

  const bf16_t* Xg = X + (size_t)wid * 128 * 1024;
  const bf16_t* Wg = Wpk + (size_t)h * 192 * 1024;

  // ---- phase 1: qkv = x @ W^T   (M=128, N=192, K=1024, BK=64)
  floatx4 acc[4][6] = {};
  for (int k0 = 0; k0 < 1024; k0 += 64) {
    __syncthreads();
#pragma unroll
    for (int it = 0; it < 4; ++it) {  // X: 1024 chunks of 8
      const int ch = it * 256 + tid;
      const int r  = ch >> 3;
      const int c8 = (ch & 7) ^ (r & 7);
      gld_lds16(Xg + (size_t)r * 1024 + k0 + c8 * 8,
                Xs + (it * 256 + wave * 64) * 8);
    }
#pragma unroll
    for (int it = 0; it < 6; ++it) {  // W: 1536 chunks of 8
      const int ch = it * 256 + tid;
      const int r  = ch >> 3;
      const int c8 = (ch & 7) ^ (r & 7);
      gld_lds16(Wg + (size_t)r * 1024 + k0 + c8 * 8,
                Ws + (it * 256 + wave * 64) * 8);
    }
    __syncthreads();

#pragma unroll
    for (int half = 0; half < 2; ++half) {
      bf16x8 af[4], bfr[6];
#pragma unroll
      for (int i = 0; i < 4; ++i) {
        const int row = wm + i * 16 + n16;
        af[i] = *(const bf16x8*)&Xs[row * 64 + (((half * 4 + q4) ^ (row & 7)) * 8)];
      }
#pragma unroll
      for (int j = 0; j < 6; ++j) {
        const int row = wn + j * 16 + n16;
        bfr[j] = *(const bf16x8*)&Ws[row * 64 + (((half * 4 + q4) ^ (row & 7)) * 8)];
      }
#pragma unroll
      for (int i = 0; i < 4; ++i)
#pragma unroll
        for (int j = 0; j < 6; ++j)
          acc[i][j] = MFMA_16x16x32(af[i], bfr[j], acc[i][j]);
    }
  }
  __syncthreads();  // staging region dead -> qs/ks/vsT may alias it

  // ---- epilogue: scatter acc -> qs (scaled), ks, vsT (swizzled transpose)
#pragma unroll
  for (int j = 0; j < 6; ++j) {
    const int base = wn + j * 16;   // wave-uniform
    const int col  = base + n16;    // 0..191
    const int gb = (base < 64) ? h * 64 + col
                 : (base < 128) ? 1024 + h * 64 + (col - 64)
                                : 2048 + h * 64 + (col - 128);
    const float bias = bin[gb];
#pragma unroll
    for (int i = 0; i < 4; ++i) {
      const int row0 = wm + i * 16 + q4 * 4;
      if (base < 64) {        // q, fold softmax scale 1/sqrt(64)
#pragma unroll
        for (int r = 0; r < 4; ++r)
          qs[(row0 + r) * 72 + col] = (bf16_t)((acc[i][j][r] + bias) * 0.125f);
      } else if (base < 128) {  // k
#pragma unroll
        for (int r = 0; r < 4; ++r)
          ks[(row0 + r) * 72 + (col - 64)] = (bf16_t)(acc[i][j][r] + bias);
      } else {                  // v -> transposed [dim][token], swizzled
        bf16x4 pv;
#pragma unroll
        for (int r = 0; r < 4; ++r) pv[r] = (bf16_t)(acc[i][j][r] + bias);
        const int d = col - 128;          // dim 0..63; d&15 == n16
        const int c8 = row0 >> 3, pos = row0 & 7;
        *(bf16x4*)&vsT[d * 128 + ((c8 ^ n16) << 3) + pos] = pv;
      }
    }
  }
  __syncthreads();

  // ---- S = q k^T  (wave w owns S rows [32w, 32w+32), K=64)
  floatx4 sacc[2][8] = {};
#pragma unroll
  for (int ks0 = 0; ks0 < 2; ++ks0) {
    bf16x8 aq[2];
#pragma unroll
    for (int i = 0; i < 2; ++i)
      aq[i] = *(const bf16x8*)&qs[(wave * 32 + i * 16 + n16) * 72 + ks0 * 32 + q4 * 8];
#pragma unroll
    for (int j = 0; j < 8; ++j) {
      bf16x8 bk = *(const bf16x8*)&ks[(j * 16 + n16) * 72 + ks0 * 32 + q4 * 8];
      sacc[0][j] = MFMA_16x16x32(aq[0], bk, sacc[0][j]);
      sacc[1][j] = MFMA_16x16x32(aq[1], bk, sacc[1][j]);
    }
  }
  __syncthreads();  // q/k reads done; Ps may overwrite their LDS

  // ---- softmax: no max-sub (logits bounded), P unnormalized, defer 1/sum
  float invs[2][4];
#pragma unroll
  for (int i = 0; i < 2; ++i) {
#pragma unroll
    for (int r = 0; r < 4; ++r) {
      float vals[8];
      float s = 0.f;
#pragma unroll
      for (int j = 0; j < 8; ++j) {
        vals[j] = __expf(sacc[i][j][r]);
        s += vals[j];
      }
      for (int m = 1; m < 16; m <<= 1) s += __shfl_xor(s, m, 64);
      invs[i][r] = 1.0f / s;
      const int prow = wave * 32 + i * 16 + q4 * 4 + r;
#pragma unroll
      for (int j = 0; j < 8; ++j)
        Ps[prow * 136 + j * 16 + n16] = (bf16_t)vals[j];
    }
  }
  __syncthreads();

  // ---- O = P V  (K=128; both operands via ds_read_b128)
  floatx4 oacc[2][4] = {};
#pragma unroll
  for (int kk = 0; kk < 4; ++kk) {
    bf16x8 ap[2];
#pragma unroll
    for (int i = 0; i < 2; ++i)
      ap[i] = *(const bf16x8*)&Ps[(wave * 32 + i * 16 + n16) * 136 + kk * 32 + q4 * 8];
#pragma unroll
    for (int j = 0; j < 4; ++j) {
      const int d = j * 16 + n16;
      bf16x8 bv = *(const bf16x8*)&vsT[d * 128 + (((kk * 4 + q4) ^ n16) << 3)];
      oacc[0][j] = MFMA_16x16x32(ap[0], bv, oacc[0][j]);
      oacc[1][j] = MFMA_16x16x32(ap[1], bv, oacc[1][j]);
    }
  }

  // ---- write o slice (scaled by 1/rowsum), merged-head layout [tok][h*64+d]
  bf16_t* go = o + (size_t)wid * 128 * 1024 + h * 64;
#pragma unroll
  for (int i = 0; i < 2; ++i)
#pragma unroll
    for (int j = 0; j < 4; ++j)
#pragma unroll
      for (int r = 0; r < 4; ++r) {
        const int row = wave * 32 + i * 16 + q4 * 4 + r;
        go[(size_t)row * 1024 + j * 16 + n16] = (bf16_t)(oacc[i][j][r] * invs[i][r]);
      }
}

// ---------------------------------------------------------------------------
extern "C" void kernel_launch(void* const* d_in, const int* in_sizes, int n_in,
                              void* d_out, int out_size, void* d_ws, size_t ws_size,
                              hipStream_t stream) {
  const float* x    = (const float*)d_in[0];
  const float* Win  = (const float*)d_in[1];   // [3072,1024]
  const float* bin  = (const float*)d_in[2];   // [3072]
  const float* Wout = (const float*)d_in[3];   // [1024,1024]
  const float* bout = (const float*)d_in[4];   // [1024]
  float* out = (float*)d_out;

  const size_t M = 16384, H = 1024, H3 = 3072;

  // workspace layout (~72 MB): xb | Wpk | Woutb | ob
  bf16_t* xb    = (bf16_t*)d_ws;        // M*H
  bf16_t* Wpk   = xb + M * H;           // H3*H (head-packed)
  bf16_t* Woutb = Wpk + H3 * H;         // H*H
  bf16_t* ob    = Woutb + H * H;        // M*H

  // grid-strided conversion (G11): 2048 blocks, 5 chunks/thread
  cvt_all<<<dim3(2048), 256, 0, stream>>>(x, Win, Wout, xb, Wpk, Woutb);

  // grid: window-major -> linear id = wid + 128*h -> window pins to XCD wid%8,
  // all 16 heads of a window share that XCD's L2 copy of X.
  qkv_attn<<<dim3(128, 16), 256, 0, stream>>>(xb, Wpk, bin, ob);

  // 512 blocks = one full dispatch round at 2/CU; XCD id%8 pins one B-tile.
  gemm_out<<<dim3((unsigned)(H / 256), (unsigned)(M / 128)), 256, 0, stream>>>(
      ob, Woutb, bout, out, (int)M, (int)H, (int)H);
}